// Round 1
// 198.112 us; speedup vs baseline: 1.0461x; 1.0461x over previous
//
#include <hip/hip_runtime.h>
#include <math.h>

#define NN   5000
#define INF_ 64
#define HID  32
#define NH   4
#define OUTF 64
#define NEG  0.2f
#define CAP  256   // max neighbors/row; E[deg]=101, max~150 -> safe margin

typedef float nt4 __attribute__((ext_vector_type(4)));  // native vector for nontemporal builtin

__device__ inline float wred_sum(float v) {
#pragma unroll
    for (int off = 32; off > 0; off >>= 1) v += __shfl_down(v, off, 64);
    return v;
}

// ---------------- K1: Wh1 + layer-1 scores + ballot-compacted neighbor list --
// Changes vs prev: ONE LDS atomic + readfirstlane per 4-element group (was 4),
// neighbor list staged in LDS, written out coalesced as int4 at the end.
__global__ __launch_bounds__(256) void k1(const float* __restrict__ adj,
        const float* __restrict__ h, const float* __restrict__ W1,
        const float* __restrict__ a1s, const float* __restrict__ a1d,
        int* __restrict__ counts, int* __restrict__ idx,
        float* __restrict__ Wh1, float* __restrict__ s1s, float* __restrict__ s1d) {
    const int i = blockIdx.x, t = threadIdx.x;
    const int lane = t & 63;
    __shared__ int cnt;
    __shared__ float hs[INF_];
    __shared__ int nbs[CAP];           // staged neighbor list
    if (t == 0) cnt = 0;
    if (t < INF_) hs[t] = h[i * INF_ + t];
    __syncthreads();
    // Wh1 row + scores first (waves 0-1) so W1 loads issue early
    if (t < 128) {
        float acc = 0.f;
#pragma unroll
        for (int k = 0; k < INF_; ++k) acc += hs[k] * W1[k * (NH * HID) + t];
        Wh1[(size_t)i * (NH * HID) + t] = acc;
        const int hd = t >> 5, f = t & 31;
        float vs = acc * a1s[hd * HID + f];
        float vd = acc * a1d[hd * HID + f];
#pragma unroll
        for (int off = 16; off > 0; off >>= 1) {
            vs += __shfl_down(vs, off, 32);
            vd += __shfl_down(vd, off, 32);
        }
        if (f == 0) { s1s[i * NH + hd] = vs; s1d[i * NH + hd] = vd; }
    }
    // adjacency scan: wave-ballot compaction (order-free; softmax is perm-invariant)
    const nt4* row4 = (const nt4*)(adj + (size_t)i * NN);  // 20000B rows, 16B aligned
    for (int j = t; j < NN / 4; j += 256) {
        nt4 v = __builtin_nontemporal_load(&row4[j]);
        const bool p0 = v.x > 0.f, p1 = v.y > 0.f, p2 = v.z > 0.f, p3 = v.w > 0.f;
        const unsigned long long b0 = __ballot(p0);
        const unsigned long long b1 = __ballot(p1);
        const unsigned long long b2 = __ballot(p2);
        const unsigned long long b3 = __ballot(p3);
        const int t0 = __popcll(b0), t1 = __popcll(b1), t2 = __popcll(b2), t3 = __popcll(b3);
        const int tot = t0 + t1 + t2 + t3;
        int base = 0;
        if (lane == 0 && tot) base = atomicAdd(&cnt, tot);   // one atomic per 256 elements
        base = __builtin_amdgcn_readfirstlane(base);         // SGPR broadcast, cheaper than shfl
        const unsigned long long below = (1ull << lane) - 1ull;
        if (p0) { int p = base + __popcll(b0 & below);               if (p < CAP) nbs[p] = 4 * j;     }
        if (p1) { int p = base + t0 + __popcll(b1 & below);          if (p < CAP) nbs[p] = 4 * j + 1; }
        if (p2) { int p = base + t0 + t1 + __popcll(b2 & below);     if (p < CAP) nbs[p] = 4 * j + 2; }
        if (p3) { int p = base + t0 + t1 + t2 + __popcll(b3 & below);if (p < CAP) nbs[p] = 4 * j + 3; }
    }
    __syncthreads();
    const int c = cnt < CAP ? cnt : CAP;
    if (t == 0) counts[i] = c;
    // coalesced vectorized writeout (tail garbage beyond c is never read downstream)
    int4* my4 = (int4*)(idx + (size_t)i * CAP);
    const int c4 = (c + 3) >> 2;
    for (int e = t; e < c4; e += 256) my4[e] = ((const int4*)nbs)[e];
}

// ---------------- K2: layer-1 attention + ELU + Wh2 + layer-2 scores ---------
// Changes vs prev: no max pass (scores are O(10), exp is safe in f32; softmax
// without max-shift is identical up to rounding), idx-load/score/exp/sum fused
// into ONE pass. 4 barriers instead of 8.
__global__ __launch_bounds__(256) void k2(const int* __restrict__ counts,
        const int* __restrict__ idx, const float* __restrict__ Wh1,
        const float* __restrict__ s1s, const float* __restrict__ s1d,
        const float* __restrict__ W2, const float* __restrict__ a2s,
        const float* __restrict__ a2d, float* __restrict__ Wh2,
        float* __restrict__ s2s, float* __restrict__ s2d) {
    const int i = blockIdx.x, t = threadIdx.x;
    const int lane = t & 63, wave = t >> 6;
    const int c = counts[i];
    __shared__ int   nb[CAP];
    __shared__ float sc[NH][CAP];     // transposed: conflict-free strided passes
    __shared__ float aggf[4][128];
    __shared__ float xs[128];
    __shared__ float redh[4 * NH];
    __shared__ float pw[4][64];
    const float4 ss = ((const float4*)s1s)[i];       // broadcast
    const float4* s1d4 = (const float4*)s1d;
    const int* my = idx + (size_t)i * CAP;
    float l0 = 0.f, l1 = 0.f, l2 = 0.f, l3 = 0.f;
    // fused pass: neighbor load + score + exp + partial sum
    for (int e = t; e < c; e += 256) {
        const int j = my[e];
        nb[e] = j;
        const float4 sd = s1d4[j];                   // one 16B gather for all 4 heads
        float v0 = ss.x + sd.x, v1 = ss.y + sd.y, v2 = ss.z + sd.z, v3 = ss.w + sd.w;
        v0 = (v0 >= 0.f) ? v0 : NEG * v0;
        v1 = (v1 >= 0.f) ? v1 : NEG * v1;
        v2 = (v2 >= 0.f) ? v2 : NEG * v2;
        v3 = (v3 >= 0.f) ? v3 : NEG * v3;
        const float p0 = __expf(v0), p1 = __expf(v1), p2 = __expf(v2), p3 = __expf(v3);
        sc[0][e] = p0; sc[1][e] = p1; sc[2][e] = p2; sc[3][e] = p3;
        l0 += p0; l1 += p1; l2 += p2; l3 += p3;
    }
    l0 = wred_sum(l0); l1 = wred_sum(l1); l2 = wred_sum(l2); l3 = wred_sum(l3);
    if (lane == 0) {
        redh[wave * NH + 0] = l0; redh[wave * NH + 1] = l1;
        redh[wave * NH + 2] = l2; redh[wave * NH + 3] = l3;
    }
    __syncthreads();   // barrier 1: nb, sc, redh ready
    // aggregate: wave = edge-chunk; lane covers features (2*lane, 2*lane+1); x4 unroll
    {
        const float2* Wh1v = (const float2*)Wh1;     // row j at j*64 float2s
        const int hd = lane >> 4;                    // head of feature 2*lane
        const int q = (((c + 3) >> 2) + 3) & ~3;
        const int e0 = wave * q, e1 = min(c, e0 + q);
        float2 a0 = {0.f, 0.f}, a1 = {0.f, 0.f}, a2 = {0.f, 0.f}, a3 = {0.f, 0.f};
        int e = e0;
        for (; e + 3 < e1; e += 4) {
            const int j0 = nb[e], j1 = nb[e + 1], j2 = nb[e + 2], j3 = nb[e + 3];
            const float2 w0 = Wh1v[(size_t)j0 * 64 + lane];
            const float2 w1 = Wh1v[(size_t)j1 * 64 + lane];
            const float2 w2 = Wh1v[(size_t)j2 * 64 + lane];
            const float2 w3 = Wh1v[(size_t)j3 * 64 + lane];
            const float p0 = sc[hd][e], p1 = sc[hd][e + 1], p2 = sc[hd][e + 2], p3 = sc[hd][e + 3];
            a0.x += p0 * w0.x; a0.y += p0 * w0.y;
            a1.x += p1 * w1.x; a1.y += p1 * w1.y;
            a2.x += p2 * w2.x; a2.y += p2 * w2.y;
            a3.x += p3 * w3.x; a3.y += p3 * w3.y;
        }
        for (; e < e1; ++e) {
            const float2 w = Wh1v[(size_t)nb[e] * 64 + lane];
            const float p = sc[hd][e];
            a0.x += p * w.x; a0.y += p * w.y;
        }
        aggf[wave][2 * lane]     = (a0.x + a1.x) + (a2.x + a3.x);
        aggf[wave][2 * lane + 1] = (a0.y + a1.y) + (a2.y + a3.y);
    }
    __syncthreads();   // barrier 2
    if (t < 128) {
        const int hh = t >> 5;
        const float lh = redh[hh] + redh[NH + hh] + redh[2 * NH + hh] + redh[3 * NH + hh];
        float o = aggf[0][t] + aggf[1][t] + aggf[2][t] + aggf[3][t];
        o = o / lh;
        o = (o > 0.f) ? o : expm1f(o);   // ELU
        xs[t] = o;
    }
    __syncthreads();   // barrier 3
    // Wh2 row: 4 k-chunks of 32 x 64 outputs
    {
        float pa = 0.f;
#pragma unroll
        for (int k = 0; k < 32; ++k)
            pa += xs[wave * 32 + k] * W2[(wave * 32 + k) * OUTF + lane];
        pw[wave][lane] = pa;
    }
    __syncthreads();   // barrier 4
    if (t < 64) {
        float w = pw[0][t] + pw[1][t] + pw[2][t] + pw[3][t];
        Wh2[(size_t)i * OUTF + t] = w;
        float vs = wred_sum(w * a2s[t]);
        float vd = wred_sum(w * a2d[t]);
        if (t == 0) { s2s[i] = vs; s2d[i] = vd; }
    }
}

// ---------------- K3: layer-2 attention -> d_out -----------------------------
// Changes vs prev: no max pass, fused neighbor/score/exp/sum pass, 2 barriers.
__global__ __launch_bounds__(256) void k3(const int* __restrict__ counts,
        const int* __restrict__ idx, const float* __restrict__ Wh2,
        const float* __restrict__ s2s, const float* __restrict__ s2d,
        float* __restrict__ out) {
    const int i = blockIdx.x, t = threadIdx.x;
    const int lane = t & 63, wave = t >> 6;
    const int c = counts[i];
    __shared__ int   nb[CAP];
    __shared__ float sc[CAP];
    __shared__ float red[4];
    __shared__ float agg[4][64];
    const float si = s2s[i];
    const int* my = idx + (size_t)i * CAP;
    float lsum = 0.f;
    for (int e = t; e < c; e += 256) {
        const int j = my[e];
        nb[e] = j;
        float v = si + s2d[j];
        v = (v >= 0.f) ? v : NEG * v;
        const float p = __expf(v);
        sc[e] = p;
        lsum += p;
    }
    lsum = wred_sum(lsum);
    if (lane == 0) red[wave] = lsum;
    __syncthreads();   // barrier 1: nb, sc, red ready
    const int q = (((c + 3) >> 2) + 3) & ~3;
    const int e0 = wave * q, e1 = min(c, e0 + q);
    float a0 = 0.f, a1 = 0.f, a2 = 0.f, a3 = 0.f;
    int e = e0;
    for (; e + 3 < e1; e += 4) {
        a0 += sc[e]     * Wh2[(size_t)nb[e]     * OUTF + lane];
        a1 += sc[e + 1] * Wh2[(size_t)nb[e + 1] * OUTF + lane];
        a2 += sc[e + 2] * Wh2[(size_t)nb[e + 2] * OUTF + lane];
        a3 += sc[e + 3] * Wh2[(size_t)nb[e + 3] * OUTF + lane];
    }
    for (; e < e1; ++e) a0 += sc[e] * Wh2[(size_t)nb[e] * OUTF + lane];
    agg[wave][lane] = (a0 + a1) + (a2 + a3);
    __syncthreads();   // barrier 2
    if (t < 64) {
        const float ls = red[0] + red[1] + red[2] + red[3];
        float s = agg[0][t] + agg[1][t] + agg[2][t] + agg[3][t];
        out[(size_t)i * OUTF + t] = s / ls;
    }
}

extern "C" void kernel_launch(void* const* d_in, const int* in_sizes, int n_in,
                              void* d_out, int out_size, void* d_ws, size_t ws_size,
                              hipStream_t stream) {
    const float* adj = (const float*)d_in[0];
    const float* h   = (const float*)d_in[1];
    const float* W1  = (const float*)d_in[2];
    const float* a1s = (const float*)d_in[3];
    const float* a1d = (const float*)d_in[4];
    const float* W2  = (const float*)d_in[5];
    const float* a2s = (const float*)d_in[6];
    const float* a2d = (const float*)d_in[7];
    float* out = (float*)d_out;

    char* p = (char*)d_ws;
    float* Wh1 = (float*)p; p += (size_t)NN * 128 * 4;
    float* Wh2 = (float*)p; p += (size_t)NN * OUTF * 4;
    float* s1s = (float*)p; p += (size_t)NN * NH * 4;
    float* s1d = (float*)p; p += (size_t)NN * NH * 4;
    float* s2s = (float*)p; p += (size_t)NN * 4;
    float* s2d = (float*)p; p += (size_t)NN * 4;
    int*   cnt = (int*)p;   p += (size_t)NN * 4;
    int*   idx = (int*)p;   p += (size_t)NN * CAP * 4;

    k1<<<NN, 256, 0, stream>>>(adj, h, W1, a1s, a1d, cnt, idx, Wh1, s1s, s1d);
    k2<<<NN, 256, 0, stream>>>(cnt, idx, Wh1, s1s, s1d, W2, a2s, a2d, Wh2, s2s, s2d);
    k3<<<NN, 256, 0, stream>>>(cnt, idx, Wh2, s2s, s2d, out);
}

// Round 2
// 189.402 us; speedup vs baseline: 1.0942x; 1.0460x over previous
//
#include <hip/hip_runtime.h>
#include <math.h>

#define NN   5000
#define INF_ 64
#define HID  32
#define NH   4
#define OUTF 64
#define NEG  0.2f
#define CAP  256   // max neighbors/row; E[deg]=101, max~150 -> safe margin

typedef float nt4 __attribute__((ext_vector_type(4)));  // native vector for nontemporal builtin

__device__ inline float wred_sum(float v) {
#pragma unroll
    for (int off = 32; off > 0; off >>= 1) v += __shfl_down(v, off, 64);
    return v;
}

__device__ inline unsigned mask4(nt4 v) {
    return (v.x > 0.f ? 1u : 0u) | (v.y > 0.f ? 2u : 0u) |
           (v.z > 0.f ? 4u : 0u) | (v.w > 0.f ? 8u : 0u);
}

// ---------------- K1: Wh1 + layer-1 scores + compacted neighbor list ---------
// All 5 adjacency loads issued up-front into registers (5 KB/wave in flight),
// THEN masks -> one wave prefix-sum -> per-wave LDS slot. No LDS atomic, no
// early barrier (h row broadcast via shfl instead of LDS staging).
__global__ __launch_bounds__(256) void k1(const float* __restrict__ adj,
        const float* __restrict__ h, const float* __restrict__ W1,
        const float* __restrict__ a1s, const float* __restrict__ a1d,
        int* __restrict__ counts, int* __restrict__ idx,
        float* __restrict__ Wh1, float* __restrict__ s1s, float* __restrict__ s1d) {
    const int i = blockIdx.x, t = threadIdx.x;
    const int lane = t & 63, wave = t >> 6;
    __shared__ int nbs[CAP];
    __shared__ int wt4[4];
    // decoupled streaming: all loads in flight before any consumption
    const nt4* row4 = (const nt4*)(adj + (size_t)i * NN);  // 1250 nt4 per row
    nt4 v0 = __builtin_nontemporal_load(&row4[t]);
    nt4 v1 = __builtin_nontemporal_load(&row4[t + 256]);
    nt4 v2 = __builtin_nontemporal_load(&row4[t + 512]);
    nt4 v3 = __builtin_nontemporal_load(&row4[t + 768]);
    nt4 v4 = {0.f, 0.f, 0.f, 0.f};
    if (t < NN / 4 - 1024) v4 = __builtin_nontemporal_load(&row4[t + 1024]);
    const float hreg = h[(size_t)i * INF_ + lane];   // each wave holds full h row
    // Wh1 row + scores (waves 0-1) overlap with the in-flight adjacency loads
    if (t < 128) {
        float acc = 0.f;
#pragma unroll
        for (int k = 0; k < INF_; ++k) acc += __shfl(hreg, k, 64) * W1[k * (NH * HID) + t];
        Wh1[(size_t)i * (NH * HID) + t] = acc;
        const int hd = t >> 5, f = t & 31;
        float vs = acc * a1s[hd * HID + f];
        float vd = acc * a1d[hd * HID + f];
#pragma unroll
        for (int off = 16; off > 0; off >>= 1) {
            vs += __shfl_down(vs, off, 32);
            vd += __shfl_down(vd, off, 32);
        }
        if (f == 0) { s1s[i * NH + hd] = vs; s1d[i * NH + hd] = vd; }
    }
    // 20-bit presence mask per lane, single wave prefix-sum
    const unsigned m20 = mask4(v0) | (mask4(v1) << 4) | (mask4(v2) << 8) |
                         (mask4(v3) << 12) | (mask4(v4) << 16);
    const int cl = __popc(m20);
    int incl = cl;
#pragma unroll
    for (int off = 1; off < 64; off <<= 1) {
        int u = __shfl_up(incl, off, 64);
        if (lane >= off) incl += u;
    }
    if (lane == 63) wt4[wave] = incl;     // per-wave total (race-free slot)
    __syncthreads();                       // all loads consumed by now: drain is free
    int base = 0;
#pragma unroll
    for (int w = 0; w < 4; ++w) base += (w < wave) ? wt4[w] : 0;
    int p = base + (incl - cl);            // exclusive prefix within block
    unsigned m = m20;
    while (m) {
        const int b = __ffs(m) - 1; m &= m - 1;
        const int nid = 4 * (t + (b >> 2) * 256) + (b & 3);
        if (p < CAP) nbs[p] = nid;
        ++p;
    }
    __syncthreads();
    const int tot = wt4[0] + wt4[1] + wt4[2] + wt4[3];
    const int c = tot < CAP ? tot : CAP;
    if (t == 0) counts[i] = c;
    int4* my4 = (int4*)(idx + (size_t)i * CAP);
    for (int e = t; e < ((c + 3) >> 2); e += 256) my4[e] = ((const int4*)nbs)[e];
}

// ---------------- K2: layer-1 attention + ELU + Wh2 + layer-2 scores ---------
// Aggregate: float4/lane, lane halves cover 2 edges per instruction, x2 unroll
// (4 gathers = 32 cache lines in flight). Edges padded to x4 (nb=0, sc=0).
__global__ __launch_bounds__(256) void k2(const int* __restrict__ counts,
        const int* __restrict__ idx, const float* __restrict__ Wh1,
        const float* __restrict__ s1s, const float* __restrict__ s1d,
        const float* __restrict__ W2, const float* __restrict__ a2s,
        const float* __restrict__ a2d, float* __restrict__ Wh2,
        float* __restrict__ s2s, float* __restrict__ s2d) {
    const int i = blockIdx.x, t = threadIdx.x;
    const int lane = t & 63, wave = t >> 6;
    const int c = counts[i];
    const int cp = (c + 3) & ~3;
    __shared__ int   nb[CAP];
    __shared__ float sc[NH][CAP + 1];   // +1: de-alias banks for per-head reads
    __shared__ float aggf[4][128];
    __shared__ float xs[128];
    __shared__ float redh[4 * NH];
    __shared__ float pw[4][64];
    const float4 ss = ((const float4*)s1s)[i];
    const float4* s1d4 = (const float4*)s1d;
    const int* my = idx + (size_t)i * CAP;
    float l0 = 0.f, l1 = 0.f, l2 = 0.f, l3 = 0.f;
    // fused pass: neighbor load + score + exp + partial sum
    for (int e = t; e < c; e += 256) {
        const int j = my[e];
        nb[e] = j;
        const float4 sd = s1d4[j];
        float w0 = ss.x + sd.x, w1 = ss.y + sd.y, w2 = ss.z + sd.z, w3 = ss.w + sd.w;
        w0 = (w0 >= 0.f) ? w0 : NEG * w0;
        w1 = (w1 >= 0.f) ? w1 : NEG * w1;
        w2 = (w2 >= 0.f) ? w2 : NEG * w2;
        w3 = (w3 >= 0.f) ? w3 : NEG * w3;
        const float p0 = __expf(w0), p1 = __expf(w1), p2 = __expf(w2), p3 = __expf(w3);
        sc[0][e] = p0; sc[1][e] = p1; sc[2][e] = p2; sc[3][e] = p3;
        l0 += p0; l1 += p1; l2 += p2; l3 += p3;
    }
    for (int e = c + t; e < cp; e += 256) {   // zero-pad: contributes exactly 0
        nb[e] = 0;
        sc[0][e] = 0.f; sc[1][e] = 0.f; sc[2][e] = 0.f; sc[3][e] = 0.f;
    }
    l0 = wred_sum(l0); l1 = wred_sum(l1); l2 = wred_sum(l2); l3 = wred_sum(l3);
    if (lane == 0) {
        redh[wave * NH + 0] = l0; redh[wave * NH + 1] = l1;
        redh[wave * NH + 2] = l2; redh[wave * NH + 3] = l3;
    }
    __syncthreads();   // barrier 1: nb, sc, redh ready
    // aggregate: lane = (half, fi); each gather instruction covers 2 rows
    {
        const float4* Wh1v = (const float4*)Wh1;   // row j = 32 float4
        const int half = lane >> 5, fi = lane & 31, hd = fi >> 3;
        const int g4 = cp >> 2;                    // 4-edge groups
        const int gw = (g4 + 3) >> 2;              // groups per wave
        int g = wave * gw;
        const int gend = min(g4, wave * gw + gw);
        float4 a0 = {0.f,0.f,0.f,0.f}, a1 = a0, a2 = a0, a3 = a0;
        for (; g + 1 < gend; g += 2) {
            const int e = 4 * g;
            const int j0 = nb[e + half],     j1 = nb[e + 2 + half];
            const int j2 = nb[e + 4 + half], j3 = nb[e + 6 + half];
            const float p0 = sc[hd][e + half],     p1 = sc[hd][e + 2 + half];
            const float p2 = sc[hd][e + 4 + half], p3 = sc[hd][e + 6 + half];
            const float4 w0 = Wh1v[(size_t)j0 * 32 + fi];
            const float4 w1 = Wh1v[(size_t)j1 * 32 + fi];
            const float4 w2 = Wh1v[(size_t)j2 * 32 + fi];
            const float4 w3 = Wh1v[(size_t)j3 * 32 + fi];
            a0.x += p0 * w0.x; a0.y += p0 * w0.y; a0.z += p0 * w0.z; a0.w += p0 * w0.w;
            a1.x += p1 * w1.x; a1.y += p1 * w1.y; a1.z += p1 * w1.z; a1.w += p1 * w1.w;
            a2.x += p2 * w2.x; a2.y += p2 * w2.y; a2.z += p2 * w2.z; a2.w += p2 * w2.w;
            a3.x += p3 * w3.x; a3.y += p3 * w3.y; a3.z += p3 * w3.z; a3.w += p3 * w3.w;
        }
        if (g < gend) {
            const int e = 4 * g;
            const int j0 = nb[e + half], j1 = nb[e + 2 + half];
            const float p0 = sc[hd][e + half], p1 = sc[hd][e + 2 + half];
            const float4 w0 = Wh1v[(size_t)j0 * 32 + fi];
            const float4 w1 = Wh1v[(size_t)j1 * 32 + fi];
            a0.x += p0 * w0.x; a0.y += p0 * w0.y; a0.z += p0 * w0.z; a0.w += p0 * w0.w;
            a1.x += p1 * w1.x; a1.y += p1 * w1.y; a1.z += p1 * w1.z; a1.w += p1 * w1.w;
        }
        float4 aa;
        aa.x = (a0.x + a1.x) + (a2.x + a3.x);
        aa.y = (a0.y + a1.y) + (a2.y + a3.y);
        aa.z = (a0.z + a1.z) + (a2.z + a3.z);
        aa.w = (a0.w + a1.w) + (a2.w + a3.w);
        aa.x += __shfl_xor(aa.x, 32, 64);
        aa.y += __shfl_xor(aa.y, 32, 64);
        aa.z += __shfl_xor(aa.z, 32, 64);
        aa.w += __shfl_xor(aa.w, 32, 64);
        if (lane < 32) ((float4*)aggf[wave])[lane] = aa;
    }
    __syncthreads();   // barrier 2
    if (t < 128) {
        const int hh = t >> 5;
        const float lh = redh[hh] + redh[NH + hh] + redh[2 * NH + hh] + redh[3 * NH + hh];
        float o = aggf[0][t] + aggf[1][t] + aggf[2][t] + aggf[3][t];
        o = o / lh;
        o = (o > 0.f) ? o : expm1f(o);   // ELU
        xs[t] = o;
    }
    __syncthreads();   // barrier 3
    // Wh2 row: 4 k-chunks of 32 x 64 outputs
    {
        float pa = 0.f;
#pragma unroll
        for (int k = 0; k < 32; ++k)
            pa += xs[wave * 32 + k] * W2[(wave * 32 + k) * OUTF + lane];
        pw[wave][lane] = pa;
    }
    __syncthreads();   // barrier 4
    if (t < 64) {
        float w = pw[0][t] + pw[1][t] + pw[2][t] + pw[3][t];
        Wh2[(size_t)i * OUTF + t] = w;
        float vs = wred_sum(w * a2s[t]);
        float vd = wred_sum(w * a2d[t]);
        if (t == 0) { s2s[i] = vs; s2d[i] = vd; }
    }
}

// ---------------- K3: layer-2 attention -> d_out -----------------------------
// 128-thread blocks (2 waves). Aggregate: float4/lane, lane quarters cover
// 4 edges per instruction, x2 unroll (8 rows / 32 lines in flight per wave).
__global__ __launch_bounds__(128) void k3(const int* __restrict__ counts,
        const int* __restrict__ idx, const float* __restrict__ Wh2,
        const float* __restrict__ s2s, const float* __restrict__ s2d,
        float* __restrict__ out) {
    const int i = blockIdx.x, t = threadIdx.x;
    const int lane = t & 63, wave = t >> 6;
    const int c = counts[i];
    const int cp = (c + 3) & ~3;
    __shared__ int   nb[CAP];
    __shared__ float sc[CAP];
    __shared__ float red[2];
    __shared__ float agg[2][64];
    const float si = s2s[i];
    const int* my = idx + (size_t)i * CAP;
    float lsum = 0.f;
    for (int e = t; e < c; e += 128) {
        const int j = my[e];
        nb[e] = j;
        float v = si + s2d[j];
        v = (v >= 0.f) ? v : NEG * v;
        const float p = __expf(v);
        sc[e] = p;
        lsum += p;
    }
    for (int e = c + t; e < cp; e += 128) { nb[e] = 0; sc[e] = 0.f; }
    lsum = wred_sum(lsum);
    if (lane == 0) red[wave] = lsum;
    __syncthreads();   // barrier 1
    const float4* Wh2v = (const float4*)Wh2;   // row j = 16 float4
    const int qi = lane >> 4, fi = lane & 15;  // quarter-edge, float4 feature
    const int g4 = cp >> 2;                    // 4-edge groups
    const int gw = (g4 + 1) >> 1;              // groups per wave
    int g = wave * gw;
    const int gend = min(g4, wave * gw + gw);
    float4 a0 = {0.f,0.f,0.f,0.f}, a1 = a0;
    for (; g + 1 < gend; g += 2) {
        const int eA = 4 * g + qi, eB = 4 * g + 4 + qi;
        const int jA = nb[eA], jB = nb[eB];
        const float pA = sc[eA], pB = sc[eB];
        const float4 wA = Wh2v[(size_t)jA * 16 + fi];
        const float4 wB = Wh2v[(size_t)jB * 16 + fi];
        a0.x += pA * wA.x; a0.y += pA * wA.y; a0.z += pA * wA.z; a0.w += pA * wA.w;
        a1.x += pB * wB.x; a1.y += pB * wB.y; a1.z += pB * wB.z; a1.w += pB * wB.w;
    }
    if (g < gend) {
        const int eA = 4 * g + qi;
        const int jA = nb[eA];
        const float pA = sc[eA];
        const float4 wA = Wh2v[(size_t)jA * 16 + fi];
        a0.x += pA * wA.x; a0.y += pA * wA.y; a0.z += pA * wA.z; a0.w += pA * wA.w;
    }
    float4 aa;
    aa.x = a0.x + a1.x; aa.y = a0.y + a1.y; aa.z = a0.z + a1.z; aa.w = a0.w + a1.w;
#pragma unroll
    for (int off = 16; off <= 32; off <<= 1) {
        aa.x += __shfl_xor(aa.x, off, 64);
        aa.y += __shfl_xor(aa.y, off, 64);
        aa.z += __shfl_xor(aa.z, off, 64);
        aa.w += __shfl_xor(aa.w, off, 64);
    }
    if (lane < 16) ((float4*)agg[wave])[lane] = aa;
    __syncthreads();   // barrier 2
    if (t < 64) {
        const float ls = red[0] + red[1];
        const float s = agg[0][t] + agg[1][t];
        out[(size_t)i * OUTF + t] = s / ls;
    }
}

extern "C" void kernel_launch(void* const* d_in, const int* in_sizes, int n_in,
                              void* d_out, int out_size, void* d_ws, size_t ws_size,
                              hipStream_t stream) {
    const float* adj = (const float*)d_in[0];
    const float* h   = (const float*)d_in[1];
    const float* W1  = (const float*)d_in[2];
    const float* a1s = (const float*)d_in[3];
    const float* a1d = (const float*)d_in[4];
    const float* W2  = (const float*)d_in[5];
    const float* a2s = (const float*)d_in[6];
    const float* a2d = (const float*)d_in[7];
    float* out = (float*)d_out;

    char* p = (char*)d_ws;
    float* Wh1 = (float*)p; p += (size_t)NN * 128 * 4;
    float* Wh2 = (float*)p; p += (size_t)NN * OUTF * 4;
    float* s1s = (float*)p; p += (size_t)NN * NH * 4;
    float* s1d = (float*)p; p += (size_t)NN * NH * 4;
    float* s2s = (float*)p; p += (size_t)NN * 4;
    float* s2d = (float*)p; p += (size_t)NN * 4;
    int*   cnt = (int*)p;   p += (size_t)NN * 4;
    int*   idx = (int*)p;   p += (size_t)NN * CAP * 4;

    k1<<<NN, 256, 0, stream>>>(adj, h, W1, a1s, a1d, cnt, idx, Wh1, s1s, s1d);
    k2<<<NN, 256, 0, stream>>>(cnt, idx, Wh1, s1s, s1d, W2, a2s, a2d, Wh2, s2s, s2d);
    k3<<<NN, 128, 0, stream>>>(cnt, idx, Wh2, s2s, s2d, out);
}